// Round 1
// baseline (325.868 us; speedup 1.0000x reference)
//
#include <hip/hip_runtime.h>
#include <math.h>

__device__ __forceinline__ float sigmoidf_(float x) { return 1.f / (1.f + expf(-x)); }

// ---------------- k1: h = silu(g @ ctrl_w.T + ctrl_b), gn = ||g_row|| ----------------
__global__ __launch_bounds__(256) void k1_hidden(
    const float* __restrict__ grads, const float* __restrict__ ctrl_w,
    const float* __restrict__ ctrl_b, float* __restrict__ hbuf, float* __restrict__ gnbuf) {
  int e = blockIdx.x * 256 + threadIdx.x;      // 0..4095
  int i = e >> 6, j = e & 63;
  const float4* gi = (const float4*)(grads + i * 192);
  const float4* wj = (const float4*)(ctrl_w + j * 192);
  float s = 0.f;
#pragma unroll
  for (int d = 0; d < 48; ++d) {
    float4 a = gi[d], b = wj[d];
    s += a.x * b.x + a.y * b.y + a.z * b.z + a.w * b.w;
  }
  s += ctrl_b[j];
  hbuf[e] = s * sigmoidf_(s);                  // silu
  if (blockIdx.x == 0 && threadIdx.x < 64) {
    const float4* gr = (const float4*)(grads + threadIdx.x * 192);
    float ss = 0.f;
#pragma unroll
    for (int d = 0; d < 48; ++d) {
      float4 a = gr[d];
      ss += a.x * a.x + a.y * a.y + a.z * a.z + a.w * a.w;
    }
    gnbuf[threadIdx.x] = sqrtf(ss);
  }
}

// ---------------- k2: rest of controller -> wbuf[ci][co][4], bias_eff, scale_eff ----------------
__global__ __launch_bounds__(256) void k2_ctrl(
    const float* __restrict__ hbuf, const float* __restrict__ gnbuf,
    const float* __restrict__ gp_w, const float* __restrict__ gp_b,
    const float* __restrict__ gt_w, const float* __restrict__ gt_b,
    const float* __restrict__ ln_g, const float* __restrict__ ln_b,
    const float* __restrict__ ccin_w, const float* __restrict__ ccin_b,
    const float* __restrict__ ck_w, const float* __restrict__ ck_b,
    const float* __restrict__ cb_w, const float* __restrict__ cb_b,
    const float* __restrict__ cf_w, const float* __restrict__ cf_b,
    const float* __restrict__ tau_w, const float* __restrict__ tau_b,
    const float* __restrict__ q_ema, const float* __restrict__ mem_W,
    const float* __restrict__ temp_logit,
    const float* __restrict__ conv_weight, const float* __restrict__ bias,
    float* __restrict__ wbuf, float* __restrict__ beff, float* __restrict__ seff) {
  __shared__ float sh_h[64][64];
  __shared__ float sh_hm[64][64];
  __shared__ float sh_gn[64];
  __shared__ float sh_q[4416];
  __shared__ float sh_att[4][32];
  __shared__ float sh_tau[64];
  __shared__ float sh_v[4][3];
  __shared__ int sh_idx[4][3];
  __shared__ float sh_scalars[1];
  const int tid = threadIdx.x;

  // load h, gn
  for (int t = tid; t < 4096; t += 256) ((float*)sh_h)[t] = hbuf[t];
  if (tid < 64) sh_gn[tid] = gnbuf[tid];
  __syncthreads();

  // Phase B: z gate, transform gate, hm
  for (int e = tid; e < 4096; e += 256) {
    int i = e >> 6, j = e & 63;
    const float4* h4p = (const float4*)&sh_h[i][0];
    const float4* t4p = (const float4*)(gt_w + j * 64);
    const float* gpj = gp_w + j * 65;
    float zs = 0.f, ts = 0.f;
#pragma unroll
    for (int dv = 0; dv < 16; ++dv) {
      float4 h4 = h4p[dv], t4 = t4p[dv];
      ts += h4.x * t4.x + h4.y * t4.y + h4.z * t4.z + h4.w * t4.w;
      int d = dv * 4;
      zs += h4.x * gpj[d] + h4.y * gpj[d + 1] + h4.z * gpj[d + 2] + h4.w * gpj[d + 3];
    }
    zs += sh_gn[i] * gpj[64] + gp_b[j];
    ts += gt_b[j];
    float z = sigmoidf_(zs);
    float ht = ts * sigmoidf_(ts);
    sh_hm[i][j] = (1.f - z) * sh_h[i][j] + z * ht;
  }
  __syncthreads();

  // Phase C: LayerNorm per row (threads 0..63)
  if (tid < 64) {
    int i = tid;
    float mu = 0.f;
#pragma unroll 8
    for (int j = 0; j < 64; ++j) mu += sh_hm[i][j];
    mu *= (1.f / 64.f);
    float var = 0.f;
#pragma unroll 8
    for (int j = 0; j < 64; ++j) { float d = sh_hm[i][j] - mu; var += d * d; }
    var *= (1.f / 64.f);
    float inv = 1.f / sqrtf(var + 1e-5f);
#pragma unroll 8
    for (int j = 0; j < 64; ++j) sh_h[i][j] = ln_g[j] * (sh_hm[i][j] - mu) * inv + ln_b[j];
  }
  __syncthreads();

  // Phase D: calibration heads -> q (blended with q_ema); tau partials
  for (int id = tid; id < 4416; id += 256) {
    int i; const float* wrow; float b;
    if (id < 4096) { i = id >> 6; int j = id & 63; wrow = ccin_w + j * 64; b = ccin_b[j]; }
    else if (id < 4288) { int t = id - 4096; i = t / 3; int k = t - i * 3; wrow = ck_w + k * 64; b = ck_b[k]; }
    else if (id < 4352) { i = id - 4288; wrow = cb_w; b = cb_b[0]; }
    else { i = id - 4352; wrow = cf_w; b = cf_b[0]; }
    const float4* h4p = (const float4*)&sh_h[i][0];
    const float4* w4p = (const float4*)wrow;
    float s = 0.f;
#pragma unroll
    for (int dv = 0; dv < 16; ++dv) {
      float4 h4 = h4p[dv], w4 = w4p[dv];
      s += h4.x * w4.x + h4.y * w4.y + h4.z * w4.z + h4.w * w4.w;
    }
    float val = 2.f * tanhf(s + b);
    sh_q[id] = 0.7f * val + 0.3f * q_ema[id];
  }
  if (tid < 64) {
    const float4* h4p = (const float4*)&sh_h[tid][0];
    const float4* w4p = (const float4*)tau_w;
    float s = 0.f;
#pragma unroll
    for (int dv = 0; dv < 16; ++dv) {
      float4 h4 = h4p[dv], w4 = w4p[dv];
      s += h4.x * w4.x + h4.y * w4.y + h4.z * w4.z + h4.w * w4.w;
    }
    sh_tau[tid] = sigmoidf_(s + tau_b[0]);
  }
  __syncthreads();

  // tau reduce (tid 255), attention scores (tid < 128)
  if (tid == 255) {
    float s = 0.f;
    for (int i = 0; i < 64; ++i) s += sh_tau[i];
    sh_scalars[0] = (s / 64.f) * 0.5f + 0.5f;
  }
  if (tid < 128) {
    int g = tid >> 5, m = tid & 31;
    const float* mw = mem_W + (size_t)g * 1104 * 32 + m;
    float s = 0.f;
    for (int d = 0; d < 1024; ++d) s += sh_q[g * 1024 + d] * mw[d * 32];
    for (int d = 0; d < 48; ++d) s += sh_q[4096 + g * 48 + d] * mw[(1024 + d) * 32];
    for (int d = 0; d < 16; ++d) s += sh_q[4288 + g * 16 + d] * mw[(1072 + d) * 32];
    for (int d = 0; d < 16; ++d) s += sh_q[4352 + g * 16 + d] * mw[(1088 + d) * 32];
    float temp = 0.6f * sigmoidf_(temp_logit[g]) + 0.2f;
    sh_att[g][m] = s / (temp + 1e-8f);
  }
  __syncthreads();

  // softmax + top-3 per group (tid < 4)
  if (tid < 4) {
    int g = tid;
    float mx = -1e30f;
    for (int m = 0; m < 32; ++m) mx = fmaxf(mx, sh_att[g][m]);
    float s = 0.f;
    for (int m = 0; m < 32; ++m) { float e = expf(sh_att[g][m] - mx); sh_att[g][m] = e; s += e; }
    float inv = 1.f / s;
    for (int m = 0; m < 32; ++m) sh_att[g][m] *= inv;
    for (int t = 0; t < 3; ++t) {
      float best = -2.f; int bi = 0;
      for (int m = 0; m < 32; ++m) { float p = sh_att[g][m]; if (p > best) { best = p; bi = m; } }
      sh_v[g][t] = best; sh_idx[g][t] = bi; sh_att[g][bi] = -2.f;
    }
  }
  __syncthreads();

  // Phase F: q = tau*q + (1-tau)*retrieved
  {
    float tau = sh_scalars[0];
    for (int id = tid; id < 4416; id += 256) {
      int g, d;
      if (id < 4096) { g = id >> 10; d = id & 1023; }
      else if (id < 4288) { int t = id - 4096; g = t / 48; d = 1024 + (t - g * 48); }
      else if (id < 4352) { int t = id - 4288; g = t >> 4; d = 1072 + (t & 15); }
      else { int t = id - 4352; g = t >> 4; d = 1088 + (t & 15); }
      const float* mw = mem_W + ((size_t)(g * 1104 + d)) * 32;
      float r = mw[sh_idx[g][0]] * sh_v[g][0] + mw[sh_idx[g][1]] * sh_v[g][1] + mw[sh_idx[g][2]] * sh_v[g][2];
      sh_q[id] = tau * sh_q[id] + (1.f - tau) * r;
    }
  }
  __syncthreads();

  // Phase G: final scaled conv weights -> wbuf[ci][co][4]; bias_eff, scale_eff
  for (int e = tid; e < 4096; e += 256) {
    int co = e & 63, ci = e >> 6;
    float sc = 1.f + sh_q[co * 64 + ci];
#pragma unroll
    for (int k = 0; k < 3; ++k) {
      float wk = 1.f + sh_q[4096 + co * 3 + k];
      wbuf[(ci * 64 + co) * 4 + k] = conv_weight[(co * 64 + ci) * 3 + k] * sc * wk;
    }
    wbuf[(ci * 64 + co) * 4 + 3] = 0.f;
  }
  if (tid < 64) {
    beff[tid] = bias[tid] * (1.f + sh_q[4288 + tid]);
    seff[tid] = 1.f + sh_q[4352 + tid];
  }
}

// ---------------- k3: conv1d K=3 same-pad, tiled ----------------
// grid: (32 l-tiles of 256, 64 batches), 256 threads.
// Each block: all 64 co x 256 l. ci staged in 4 chunks of 16.
// thread: cg = tid>>6 (16 co), lt = tid&63 ; outputs l = l0 + lt + 64*c, c=0..3
__global__ __launch_bounds__(256) void k3_conv(
    const float* __restrict__ x, const float* __restrict__ wbuf,
    const float* __restrict__ beff, const float* __restrict__ seff,
    float* __restrict__ out) {
  __shared__ float xs[16][272];
  __shared__ float ws4[4096];
  const int tid = threadIdx.x;
  const int n = blockIdx.y;
  const int l0 = blockIdx.x * 256;
  const int cg = tid >> 6;
  const int lt = tid & 63;

  float acc[16][4];
#pragma unroll
  for (int co = 0; co < 16; ++co)
#pragma unroll
    for (int c = 0; c < 4; ++c) acc[co][c] = 0.f;

  for (int cc = 0; cc < 4; ++cc) {
    if (cc) __syncthreads();
    // stage weights chunk: contiguous 4096 floats
    {
      const float4* wsrc = (const float4*)(wbuf + cc * 4096);
      float4* wdst = (float4*)ws4;
#pragma unroll
      for (int it = 0; it < 4; ++it) wdst[tid + it * 256] = wsrc[tid + it * 256];
    }
    // stage x: xs[ci][j] = x[n][cc*16+ci][l0 + j - 4], j in [0,272)
    {
      int ci = tid >> 4, sub = tid & 15;
      const float* row = x + ((size_t)(n * 64 + cc * 16 + ci)) * 8192;
      for (int jv = sub; jv < 68; jv += 16) {
        int j = jv * 4;
        int gl = l0 - 4 + j;
        float4 v;
        if (gl >= 0 && gl <= 8188) {
          v = *(const float4*)(row + gl);
        } else {
          v.x = ((unsigned)gl < 8192u) ? row[gl] : 0.f;
          v.y = ((unsigned)(gl + 1) < 8192u) ? row[gl + 1] : 0.f;
          v.z = ((unsigned)(gl + 2) < 8192u) ? row[gl + 2] : 0.f;
          v.w = ((unsigned)(gl + 3) < 8192u) ? row[gl + 3] : 0.f;
        }
        *(float4*)&xs[ci][j] = v;
      }
    }
    __syncthreads();

    for (int ci = 0; ci < 16; ++ci) {
      float xv[12];
#pragma unroll
      for (int c = 0; c < 4; ++c)
#pragma unroll
        for (int d = 0; d < 3; ++d) xv[c * 3 + d] = xs[ci][lt + 64 * c + 3 + d];
#pragma unroll
      for (int co = 0; co < 16; ++co) {
        const float4 wv = *(const float4*)&ws4[(ci * 64 + cg * 16 + co) * 4];
#pragma unroll
        for (int c = 0; c < 4; ++c)
          acc[co][c] += wv.x * xv[c * 3] + wv.y * xv[c * 3 + 1] + wv.z * xv[c * 3 + 2];
      }
    }
  }

  // epilogue
#pragma unroll
  for (int co = 0; co < 16; ++co) {
    int cog = cg * 16 + co;
    float be = beff[cog], se = seff[cog];
    float* orow = out + ((size_t)(n * 64 + cog)) * 8192 + l0;
#pragma unroll
    for (int c = 0; c < 4; ++c) orow[lt + 64 * c] = se * (acc[co][c] + be);
  }
}

extern "C" void kernel_launch(void* const* d_in, const int* in_sizes, int n_in,
                              void* d_out, int out_size, void* d_ws, size_t ws_size,
                              hipStream_t stream) {
  const float* x = (const float*)d_in[0];
  const float* conv_weight = (const float*)d_in[1];
  const float* bias = (const float*)d_in[2];
  const float* grads = (const float*)d_in[3];
  const float* q_ema = (const float*)d_in[4];
  const float* ctrl_w = (const float*)d_in[5];
  const float* ctrl_b = (const float*)d_in[6];
  const float* gp_w = (const float*)d_in[7];
  const float* gp_b = (const float*)d_in[8];
  const float* gt_w = (const float*)d_in[9];
  const float* gt_b = (const float*)d_in[10];
  const float* ln_g = (const float*)d_in[11];
  const float* ln_b = (const float*)d_in[12];
  const float* ccin_w = (const float*)d_in[13];
  const float* ccin_b = (const float*)d_in[14];
  const float* ck_w = (const float*)d_in[15];
  const float* ck_b = (const float*)d_in[16];
  const float* cb_w = (const float*)d_in[17];
  const float* cb_b = (const float*)d_in[18];
  const float* cf_w = (const float*)d_in[19];
  const float* cf_b = (const float*)d_in[20];
  const float* tau_w = (const float*)d_in[21];
  const float* tau_b = (const float*)d_in[22];
  const float* mem_W = (const float*)d_in[23];
  const float* temp_logit = (const float*)d_in[24];

  float* ws = (float*)d_ws;
  float* hbuf = ws;          // 4096
  float* gnbuf = ws + 4096;  // 64
  float* wbuf = ws + 4224;   // 16384 (16B-aligned offset)
  float* beff = ws + 20608;  // 64
  float* seff = ws + 20672;  // 64

  hipLaunchKernelGGL(k1_hidden, dim3(16), dim3(256), 0, stream, grads, ctrl_w, ctrl_b, hbuf, gnbuf);
  hipLaunchKernelGGL(k2_ctrl, dim3(1), dim3(256), 0, stream,
                     hbuf, gnbuf, gp_w, gp_b, gt_w, gt_b, ln_g, ln_b,
                     ccin_w, ccin_b, ck_w, ck_b, cb_w, cb_b, cf_w, cf_b,
                     tau_w, tau_b, q_ema, mem_W, temp_logit, conv_weight, bias,
                     wbuf, beff, seff);
  hipLaunchKernelGGL(k3_conv, dim3(32, 64), dim3(256), 0, stream,
                     x, wbuf, beff, seff, (float*)d_out);
}

// Round 2
// 190.985 us; speedup vs baseline: 1.7062x; 1.7062x over previous
//
#include <hip/hip_runtime.h>
#include <math.h>

typedef __attribute__((ext_vector_type(8))) short bf16x8;
typedef __attribute__((ext_vector_type(4))) float f32x4;

__device__ __forceinline__ float sigmoidf_(float x) { return 1.f / (1.f + expf(-x)); }

__device__ __forceinline__ unsigned short f2bf(float f) {
  unsigned int u = __float_as_uint(f);
  u += 0x7fffu + ((u >> 16) & 1u);   // round-to-nearest-even
  return (unsigned short)(u >> 16);
}

// ---------------- k1: h = silu(g @ ctrl_w.T + ctrl_b), gn = ||g_row|| ----------------
__global__ __launch_bounds__(256) void k1_hidden(
    const float* __restrict__ grads, const float* __restrict__ ctrl_w,
    const float* __restrict__ ctrl_b, float* __restrict__ hbuf, float* __restrict__ gnbuf) {
  int e = blockIdx.x * 256 + threadIdx.x;      // 0..4095
  int i = e >> 6, j = e & 63;
  const float4* gi = (const float4*)(grads + i * 192);
  const float4* wj = (const float4*)(ctrl_w + j * 192);
  float s = 0.f;
#pragma unroll
  for (int d = 0; d < 48; ++d) {
    float4 a = gi[d], b = wj[d];
    s += a.x * b.x + a.y * b.y + a.z * b.z + a.w * b.w;
  }
  s += ctrl_b[j];
  hbuf[e] = s * sigmoidf_(s);                  // silu
  if (blockIdx.x == 0 && threadIdx.x < 64) {
    const float4* gr = (const float4*)(grads + threadIdx.x * 192);
    float ss = 0.f;
#pragma unroll
    for (int d = 0; d < 48; ++d) {
      float4 a = gr[d];
      ss += a.x * a.x + a.y * a.y + a.z * a.z + a.w * a.w;
    }
    gnbuf[threadIdx.x] = sqrtf(ss);
  }
}

// grouped-q index helper: flat id -> (g,d) -> qg[g*1104+d]
__device__ __forceinline__ float qat_(const float* qg, int id) {
  int g, d;
  if (id < 4096) { g = id >> 10; d = id & 1023; }
  else if (id < 4288) { int t = id - 4096; g = t / 48; d = 1024 + t - g * 48; }
  else if (id < 4352) { int t = id - 4288; g = t >> 4; d = 1072 + (t & 15); }
  else { int t = id - 4352; g = t >> 4; d = 1088 + (t & 15); }
  return qg[g * 1104 + d];
}

// ---------------- k2: controller -> wfrag (bf16 MFMA B-frag layout), beff, seff ----------------
__global__ __launch_bounds__(256) void k2_ctrl(
    const float* __restrict__ hbuf, const float* __restrict__ gnbuf,
    const float* __restrict__ gp_w, const float* __restrict__ gp_b,
    const float* __restrict__ gt_w, const float* __restrict__ gt_b,
    const float* __restrict__ ln_g, const float* __restrict__ ln_b,
    const float* __restrict__ ccin_w, const float* __restrict__ ccin_b,
    const float* __restrict__ ck_w, const float* __restrict__ ck_b,
    const float* __restrict__ cb_w, const float* __restrict__ cb_b,
    const float* __restrict__ cf_w, const float* __restrict__ cf_b,
    const float* __restrict__ tau_w, const float* __restrict__ tau_b,
    const float* __restrict__ q_ema, const float* __restrict__ mem_W,
    const float* __restrict__ temp_logit,
    const float* __restrict__ conv_weight, const float* __restrict__ bias,
    unsigned short* __restrict__ wfrag, float* __restrict__ beff, float* __restrict__ seff) {
  __shared__ float sh_h[64][64];
  __shared__ float sh_hm[64][64];
  __shared__ float sh_gn[64];
  __shared__ float sh_qg[4416];      // grouped [g][1104]
  __shared__ float sh_part[4][8][32];
  __shared__ float sh_att[4][32];
  __shared__ float sh_tau[64];
  __shared__ float sh_v[4][3];
  __shared__ int sh_idx[4][3];
  __shared__ float sh_scalars[1];
  const int tid = threadIdx.x;

  for (int t = tid; t < 4096; t += 256) ((float*)sh_h)[t] = hbuf[t];
  if (tid < 64) sh_gn[tid] = gnbuf[tid];
  __syncthreads();

  // Phase B: z gate, transform gate, hm
  for (int e = tid; e < 4096; e += 256) {
    int i = e >> 6, j = e & 63;
    const float4* h4p = (const float4*)&sh_h[i][0];
    const float4* t4p = (const float4*)(gt_w + j * 64);
    const float* gpj = gp_w + j * 65;
    float zs = 0.f, ts = 0.f;
#pragma unroll
    for (int dv = 0; dv < 16; ++dv) {
      float4 h4 = h4p[dv], t4 = t4p[dv];
      ts += h4.x * t4.x + h4.y * t4.y + h4.z * t4.z + h4.w * t4.w;
      int d = dv * 4;
      zs += h4.x * gpj[d] + h4.y * gpj[d + 1] + h4.z * gpj[d + 2] + h4.w * gpj[d + 3];
    }
    zs += sh_gn[i] * gpj[64] + gp_b[j];
    ts += gt_b[j];
    float z = sigmoidf_(zs);
    float ht = ts * sigmoidf_(ts);
    sh_hm[i][j] = (1.f - z) * sh_h[i][j] + z * ht;
  }
  __syncthreads();

  // Phase C: LayerNorm per row
  if (tid < 64) {
    int i = tid;
    float mu = 0.f;
#pragma unroll 8
    for (int j = 0; j < 64; ++j) mu += sh_hm[i][j];
    mu *= (1.f / 64.f);
    float var = 0.f;
#pragma unroll 8
    for (int j = 0; j < 64; ++j) { float d = sh_hm[i][j] - mu; var += d * d; }
    var *= (1.f / 64.f);
    float inv = 1.f / sqrtf(var + 1e-5f);
#pragma unroll 8
    for (int j = 0; j < 64; ++j) sh_h[i][j] = ln_g[j] * (sh_hm[i][j] - mu) * inv + ln_b[j];
  }
  __syncthreads();

  // Phase D: calibration heads -> sh_qg (grouped), blended with q_ema; tau partials
  for (int id = tid; id < 4416; id += 256) {
    int i; const float* wrow; float b;
    if (id < 4096) { i = id >> 6; int jj = id & 63; wrow = ccin_w + jj * 64; b = ccin_b[jj]; }
    else if (id < 4288) { int t = id - 4096; i = t / 3; int k = t - i * 3; wrow = ck_w + k * 64; b = ck_b[k]; }
    else if (id < 4352) { i = id - 4288; wrow = cb_w; b = cb_b[0]; }
    else { i = id - 4352; wrow = cf_w; b = cf_b[0]; }
    const float4* h4p = (const float4*)&sh_h[i][0];
    const float4* w4p = (const float4*)wrow;
    float s = 0.f;
#pragma unroll
    for (int dv = 0; dv < 16; ++dv) {
      float4 h4 = h4p[dv], w4 = w4p[dv];
      s += h4.x * w4.x + h4.y * w4.y + h4.z * w4.z + h4.w * w4.w;
    }
    float val = 2.f * tanhf(s + b);
    int g, d;
    if (id < 4096) { g = id >> 10; d = id & 1023; }
    else if (id < 4288) { int t = id - 4096; g = t / 48; d = 1024 + t - g * 48; }
    else if (id < 4352) { int t = id - 4288; g = t >> 4; d = 1072 + (t & 15); }
    else { int t = id - 4352; g = t >> 4; d = 1088 + (t & 15); }
    sh_qg[g * 1104 + d] = 0.7f * val + 0.3f * q_ema[id];
  }
  if (tid < 64) {
    const float4* h4p = (const float4*)&sh_h[tid][0];
    const float4* w4p = (const float4*)tau_w;
    float s = 0.f;
#pragma unroll
    for (int dv = 0; dv < 16; ++dv) {
      float4 h4 = h4p[dv], w4 = w4p[dv];
      s += h4.x * w4.x + h4.y * w4.y + h4.z * w4.z + h4.w * w4.w;
    }
    sh_tau[tid] = sigmoidf_(s + tau_b[0]);
  }
  __syncthreads();

  // attention partials: coalesced over mem_W, 256 threads
  {
    int m = tid & 31, j = tid >> 5;  // j 0..7
    for (int g = 0; g < 4; ++g) {
      const float* mw = mem_W + (size_t)g * 1104 * 32 + m;
      const float* qg = sh_qg + g * 1104;
      float s0 = 0.f, s1 = 0.f;
      for (int d = j; d < 1104 - 8; d += 16) {
        s0 += qg[d] * mw[(size_t)d * 32];
        s1 += qg[d + 8] * mw[(size_t)(d + 8) * 32];
      }
      // tail (1104 = 69*16, j<8 -> loop covers d up to 1095+? handle remainder safely)
      for (int d = j + ((1104 - 8 - j - 1) / 16 + 1) * 16; d < 1104; d += 8)
        s0 += qg[d] * mw[(size_t)d * 32];
      sh_part[g][j][m] = s0 + s1;
    }
    if (tid == 255) {
      float s = 0.f;
      for (int i = 0; i < 64; ++i) s += sh_tau[i];
      sh_scalars[0] = (s / 64.f) * 0.5f + 0.5f;
    }
  }
  __syncthreads();

  if (tid < 128) {
    int g = tid >> 5, m = tid & 31;
    float s = 0.f;
#pragma unroll
    for (int j = 0; j < 8; ++j) s += sh_part[g][j][m];
    float temp = 0.6f * sigmoidf_(temp_logit[g]) + 0.2f;
    sh_att[g][m] = s / (temp + 1e-8f);
  }
  __syncthreads();

  // softmax + top-3 per group
  if (tid < 4) {
    int g = tid;
    float mx = -1e30f;
    for (int m = 0; m < 32; ++m) mx = fmaxf(mx, sh_att[g][m]);
    float s = 0.f;
    for (int m = 0; m < 32; ++m) { float e = expf(sh_att[g][m] - mx); sh_att[g][m] = e; s += e; }
    float inv = 1.f / s;
    for (int m = 0; m < 32; ++m) sh_att[g][m] *= inv;
    for (int t = 0; t < 3; ++t) {
      float best = -2.f; int bi = 0;
      for (int m = 0; m < 32; ++m) { float p = sh_att[g][m]; if (p > best) { best = p; bi = m; } }
      sh_v[g][t] = best; sh_idx[g][t] = bi; sh_att[g][bi] = -2.f;
    }
  }
  __syncthreads();

  // Phase F: q = tau*q + (1-tau)*retrieved  (grouped layout)
  {
    float tau = sh_scalars[0];
    for (int id = tid; id < 4416; id += 256) {
      int g, d;
      if (id < 4096) { g = id >> 10; d = id & 1023; }
      else if (id < 4288) { int t = id - 4096; g = t / 48; d = 1024 + t - g * 48; }
      else if (id < 4352) { int t = id - 4288; g = t >> 4; d = 1072 + (t & 15); }
      else { int t = id - 4352; g = t >> 4; d = 1088 + (t & 15); }
      const float* mw = mem_W + ((size_t)(g * 1104 + d)) * 32;
      float r = mw[sh_idx[g][0]] * sh_v[g][0] + mw[sh_idx[g][1]] * sh_v[g][1] + mw[sh_idx[g][2]] * sh_v[g][2];
      sh_qg[g * 1104 + d] = tau * sh_qg[g * 1104 + d] + (1.f - tau) * r;
    }
  }
  __syncthreads();

  // Phase G: pack W into bf16 MFMA B-fragment layout.
  // wfrag flat idx = s*2048 + w*512 + lane*8 + j
  // B[k][col]: col = co_local = lane&15 (co = 16w + col), k = 32s + 8*(lane>>4) + j
  // kidx -> kk = kidx>>6, ci = kidx&63  (K ordering kk*64+ci)
  for (int f = tid; f < 12288; f += 256) {
    int j = f & 7, lane = (f >> 3) & 63, w = (f >> 9) & 3, s = f >> 11;
    int co = 16 * w + (lane & 15);
    int kidx = 32 * s + 8 * (lane >> 4) + j;
    int ci = kidx & 63, kk = kidx >> 6;
    float val = conv_weight[(co * 64 + ci) * 3 + kk]
              * (1.f + qat_(sh_qg, co * 64 + ci))
              * (1.f + qat_(sh_qg, 4096 + co * 3 + kk));
    wfrag[f] = f2bf(val);
  }
  if (tid < 64) {
    beff[tid] = bias[tid] * (1.f + sh_qg[(tid >> 4) * 1104 + 1072 + (tid & 15)]);
    seff[tid] = 1.f + sh_qg[(tid >> 4) * 1104 + 1088 + (tid & 15)];
  }
}

// ---------------- k3: conv1d as implicit GEMM via MFMA ----------------
// grid (32 l-tiles of 256, 64 batches), 256 threads = 4 waves.
// Wave w: co in [16w,16w+16), pos in [l0, l0+256). A = X (pos x K), B = W (K x co).
// LDS xs[pos][ci] bf16, row stride 72 (pos idx 0 <-> global l0-1).
__global__ __launch_bounds__(256, 3) void k3_mfma(
    const float* __restrict__ x, const unsigned short* __restrict__ wfrag,
    const float* __restrict__ beff, const float* __restrict__ seff,
    float* __restrict__ out) {
  __shared__ unsigned short xs[258 * 72];
  const int tid = threadIdx.x;
  const int w = tid >> 6, l = tid & 63;
  const int n = blockIdx.y;
  const int l0 = blockIdx.x * 256;

  // load the 6 W B-fragments for this wave's co-slice
  bf16x8 wf[6];
#pragma unroll
  for (int s = 0; s < 6; ++s)
    wf[s] = *(const bf16x8*)(wfrag + s * 2048 + w * 512 + l * 8);

  // stage x -> LDS (transposed, fp32 -> bf16)
  {
    const int ci = 16 * w + (l & 15);
    const float* row = x + ((size_t)(n * 64 + ci)) * 8192 + l0;
    unsigned short* col = xs + ci;
#pragma unroll
    for (int cc = 0; cc < 16; ++cc) {
      int c = 4 * cc + (l >> 4);
      float4 v = *(const float4*)(row + 4 * c);
      col[(1 + 4 * c) * 72] = f2bf(v.x);
      col[(2 + 4 * c) * 72] = f2bf(v.y);
      col[(3 + 4 * c) * 72] = f2bf(v.z);
      col[(4 + 4 * c) * 72] = f2bf(v.w);
    }
    if (tid < 128) {
      int ci2 = tid >> 1, side = tid & 1;
      int gp = side ? (l0 + 256) : (l0 - 1);
      float v = (gp >= 0 && gp < 8192) ? x[((size_t)(n * 64 + ci2)) * 8192 + gp] : 0.f;
      xs[(side ? 257 : 0) * 72 + ci2] = f2bf(v);
    }
  }
  __syncthreads();

  f32x4 acc[16];
#pragma unroll
  for (int t = 0; t < 16; ++t) acc[t] = (f32x4){0.f, 0.f, 0.f, 0.f};

#pragma unroll
  for (int s = 0; s < 6; ++s) {
    const int kk = s >> 1;
    const int coff = (s & 1) * 32 + 8 * (l >> 4);  // ci offset (bf16 units)
    const int pbase = (l & 15) + kk;
#pragma unroll
    for (int nt = 0; nt < 16; ++nt) {
      bf16x8 a = *(const bf16x8*)(xs + (nt * 16 + pbase) * 72 + coff);
      acc[nt] = __builtin_amdgcn_mfma_f32_16x16x32_bf16(a, wf[s], acc[nt], 0, 0, 0);
    }
  }

  // epilogue: lane l -> co = 16w + (l&15); pos = l0 + nt*16 + (l>>4)*4 + reg
  const int co = 16 * w + (l & 15);
  const float be = beff[co], se = seff[co];
  float* orow = out + ((size_t)(n * 64 + co)) * 8192 + l0 + (l >> 4) * 4;
#pragma unroll
  for (int nt = 0; nt < 16; ++nt) {
    float4 o;
    o.x = se * (acc[nt][0] + be);
    o.y = se * (acc[nt][1] + be);
    o.z = se * (acc[nt][2] + be);
    o.w = se * (acc[nt][3] + be);
    *(float4*)(orow + nt * 16) = o;
  }
}

extern "C" void kernel_launch(void* const* d_in, const int* in_sizes, int n_in,
                              void* d_out, int out_size, void* d_ws, size_t ws_size,
                              hipStream_t stream) {
  const float* x = (const float*)d_in[0];
  const float* conv_weight = (const float*)d_in[1];
  const float* bias = (const float*)d_in[2];
  const float* grads = (const float*)d_in[3];
  const float* q_ema = (const float*)d_in[4];
  const float* ctrl_w = (const float*)d_in[5];
  const float* ctrl_b = (const float*)d_in[6];
  const float* gp_w = (const float*)d_in[7];
  const float* gp_b = (const float*)d_in[8];
  const float* gt_w = (const float*)d_in[9];
  const float* gt_b = (const float*)d_in[10];
  const float* ln_g = (const float*)d_in[11];
  const float* ln_b = (const float*)d_in[12];
  const float* ccin_w = (const float*)d_in[13];
  const float* ccin_b = (const float*)d_in[14];
  const float* ck_w = (const float*)d_in[15];
  const float* ck_b = (const float*)d_in[16];
  const float* cb_w = (const float*)d_in[17];
  const float* cb_b = (const float*)d_in[18];
  const float* cf_w = (const float*)d_in[19];
  const float* cf_b = (const float*)d_in[20];
  const float* tau_w = (const float*)d_in[21];
  const float* tau_b = (const float*)d_in[22];
  const float* mem_W = (const float*)d_in[23];
  const float* temp_logit = (const float*)d_in[24];

  float* ws = (float*)d_ws;
  float* hbuf = ws;                                // 4096 floats
  float* gnbuf = ws + 4096;                        // 64
  float* beff = ws + 4160;                         // 64
  float* seff = ws + 4224;                         // 64
  unsigned short* wfrag = (unsigned short*)(ws + 4288);  // 12288 ushort

  hipLaunchKernelGGL(k1_hidden, dim3(16), dim3(256), 0, stream, grads, ctrl_w, ctrl_b, hbuf, gnbuf);
  hipLaunchKernelGGL(k2_ctrl, dim3(1), dim3(256), 0, stream,
                     hbuf, gnbuf, gp_w, gp_b, gt_w, gt_b, ln_g, ln_b,
                     ccin_w, ccin_b, ck_w, ck_b, cb_w, cb_b, cf_w, cf_b,
                     tau_w, tau_b, q_ema, mem_W, temp_logit, conv_weight, bias,
                     wfrag, beff, seff);
  hipLaunchKernelGGL(k3_mfma, dim3(32, 64), dim3(256), 0, stream,
                     x, wfrag, beff, seff, (float*)d_out);
}

// Round 3
// 110.560 us; speedup vs baseline: 2.9474x; 1.7274x over previous
//
#include <hip/hip_runtime.h>
#include <math.h>

typedef __attribute__((ext_vector_type(8))) short bf16x8;
typedef __attribute__((ext_vector_type(4))) float f32x4;

__device__ __forceinline__ float sigmoidf_(float x) { return 1.f / (1.f + expf(-x)); }

__device__ __forceinline__ unsigned short f2bf(float f) {
  unsigned int u = __float_as_uint(f);
  u += 0x7fffu + ((u >> 16) & 1u);   // round-to-nearest-even
  return (unsigned short)(u >> 16);
}

// ws layout (float offsets)
#define WS_QG    0       // 4416 floats, grouped [g][1104]
#define WS_TAU   4416
#define WS_V     4420    // 4*3 floats
#define WS_IDX   4432    // 4*3 ints
#define WS_BEFF  4448    // 64
#define WS_SEFF  4512    // 64
#define WS_WFRAG 4608    // 12288 ushort = 6144 floats

// ================= K_A: controller (h, gates, LN, heads, tau, q-blend) =================
// 1 block x 1024 threads (16 waves). lane = output column j; wave covers 4 rows i.
__global__ __launch_bounds__(1024) void kA(
    const float* __restrict__ grads, const float* __restrict__ ctrl_w, const float* __restrict__ ctrl_b,
    const float* __restrict__ gp_w, const float* __restrict__ gp_b,
    const float* __restrict__ gt_w, const float* __restrict__ gt_b,
    const float* __restrict__ ln_g, const float* __restrict__ ln_b,
    const float* __restrict__ ccin_w, const float* __restrict__ ccin_b,
    const float* __restrict__ ck_w, const float* __restrict__ ck_b,
    const float* __restrict__ cb_w, const float* __restrict__ cb_b,
    const float* __restrict__ cf_w, const float* __restrict__ cf_b,
    const float* __restrict__ tau_w, const float* __restrict__ tau_b,
    const float* __restrict__ q_ema, float* __restrict__ ws) {
  __shared__ float rawA[8514];     // staging: ctrl half [96][66] | gtT[64][66]+gpT[65][66] | ccinT[64][66]+ext[6][64]
  __shared__ float sh_h[64 * 65];  // h -> hm -> h_ln (row stride 65)
  __shared__ float gnp[64 * 17];   // gn partials; gnp[i*17+16] = final norm
  __shared__ float taup[64];
  const int tid = threadIdx.x;
  const int j = tid & 63;
  const int wv = tid >> 6;           // 0..15
  const int i0 = wv * 4;
  const int i0u = __builtin_amdgcn_readfirstlane(i0);

  // ---- h = silu(g @ ctrl_w.T + ctrl_b), K=192 in two halves ----
  float acc[4] = {0.f, 0.f, 0.f, 0.f};
  for (int hh = 0; hh < 2; ++hh) {
    const int d0 = hh * 96;
    for (int t = tid; t < 6144; t += 1024) {
      int jj = t / 96, dl = t - jj * 96;
      rawA[dl * 66 + jj] = ctrl_w[jj * 192 + d0 + dl];
    }
    __syncthreads();
    const float* g0 = grads + i0u * 192 + d0;   // wave-uniform base -> scalar loads
#pragma unroll 8
    for (int dl = 0; dl < 96; ++dl) {
      float wvv = rawA[dl * 66 + j];
      acc[0] += wvv * g0[dl];
      acc[1] += wvv * g0[192 + dl];
      acc[2] += wvv * g0[384 + dl];
      acc[3] += wvv * g0[576 + dl];
    }
    __syncthreads();
  }
  {
    float cb_ = ctrl_b[j];
#pragma unroll
    for (int ii = 0; ii < 4; ++ii) {
      float s = acc[ii] + cb_;
      sh_h[(i0 + ii) * 65 + j] = s * sigmoidf_(s);
    }
  }
  // ---- gn partials ----
  {
    int gi = tid >> 4, seg = tid & 15;
    const float* gr = grads + gi * 192 + seg * 12;
    float ss = 0.f;
#pragma unroll
    for (int m = 0; m < 12; ++m) { float v = gr[m]; ss += v * v; }
    gnp[gi * 17 + seg] = ss;
  }
  __syncthreads();
  if (tid < 64) {
    float s = 0.f;
#pragma unroll
    for (int seg = 0; seg < 16; ++seg) s += gnp[tid * 17 + seg];
    gnp[tid * 17 + 16] = sqrtf(s);
  }
  // stage gtT, gpT
  for (int t = tid; t < 4096; t += 1024) rawA[(t & 63) * 66 + (t >> 6)] = gt_w[t];
  for (int t = tid; t < 4160; t += 1024) {
    int jj = t / 65, dd = t - jj * 65;
    rawA[4224 + dd * 66 + jj] = gp_w[t];
  }
  __syncthreads();

  // ---- phase B: z gate + transform gate -> hm (held in regs) ----
  float hm[4];
  {
    float zacc[4] = {0.f, 0.f, 0.f, 0.f}, tacc[4] = {0.f, 0.f, 0.f, 0.f};
#pragma unroll 4
    for (int d = 0; d < 64; ++d) {
      float gtv = rawA[d * 66 + j];
      float gpv = rawA[4224 + d * 66 + j];
#pragma unroll
      for (int ii = 0; ii < 4; ++ii) {
        float hv = sh_h[(i0 + ii) * 65 + d];   // uniform -> broadcast
        tacc[ii] += hv * gtv;
        zacc[ii] += hv * gpv;
      }
    }
    float gplast = rawA[4224 + 64 * 66 + j];
    float zb = gp_b[j], tb = gt_b[j];
#pragma unroll
    for (int ii = 0; ii < 4; ++ii) {
      float gn_ = gnp[(i0 + ii) * 17 + 16];
      float zs = zacc[ii] + gn_ * gplast + zb;
      float ts = tacc[ii] + tb;
      float z = sigmoidf_(zs);
      float ht = ts * sigmoidf_(ts);
      hm[ii] = (1.f - z) * sh_h[(i0 + ii) * 65 + j] + z * ht;
    }
  }
  __syncthreads();
#pragma unroll
  for (int ii = 0; ii < 4; ++ii) sh_h[(i0 + ii) * 65 + j] = hm[ii];
  __syncthreads();

  // ---- LN (in place, wave-local rows) + stage ccinT/ext ----
  {
    float lg = ln_g[j], lb = ln_b[j];
#pragma unroll
    for (int ii = 0; ii < 4; ++ii) {
      float x = sh_h[(i0 + ii) * 65 + j];
      float s = x;
#pragma unroll
      for (int off = 32; off; off >>= 1) s += __shfl_xor(s, off);
      float mu = s * (1.f / 64.f);
      float dv = x - mu;
      float v2 = dv * dv;
#pragma unroll
      for (int off = 32; off; off >>= 1) v2 += __shfl_xor(v2, off);
      float invs = 1.f / sqrtf(v2 * (1.f / 64.f) + 1e-5f);
      sh_h[(i0 + ii) * 65 + j] = lg * dv * invs + lb;
    }
  }
  for (int t = tid; t < 4096; t += 1024) rawA[(t & 63) * 66 + (t >> 6)] = ccin_w[t];
  if (tid < 384) {
    int c = tid >> 6, d = tid & 63;
    float v = (c < 3) ? ck_w[c * 64 + d] : (c == 3) ? cb_w[d] : (c == 4) ? cf_w[d] : tau_w[d];
    rawA[4224 + c * 64 + d] = v;
  }
  __syncthreads();

  // ---- phase D main: w_cin head ----
  {
    float cb_ = ccin_b[j];
    float s4[4] = {0.f, 0.f, 0.f, 0.f};
#pragma unroll 4
    for (int d = 0; d < 64; ++d) {
      float cv = rawA[d * 66 + j];
#pragma unroll
      for (int ii = 0; ii < 4; ++ii) s4[ii] += sh_h[(i0 + ii) * 65 + d] * cv;
    }
#pragma unroll
    for (int ii = 0; ii < 4; ++ii) {
      int i = i0 + ii;
      float val = 2.f * tanhf(s4[ii] + cb_);
      ws[WS_QG + (i >> 4) * 1104 + (i & 15) * 64 + j] = 0.7f * val + 0.3f * q_ema[i * 64 + j];
    }
  }
  // ---- phase D extras: ck(3), cb, cf, tau rows; lane = i ----
  if (wv < 6) {
    int i = j;
    float s = 0.f;
    const float* er = rawA + 4224 + wv * 64;
#pragma unroll 4
    for (int d = 0; d < 64; ++d) s += sh_h[i * 65 + d] * er[d];
    if (wv < 3) {
      float val = 2.f * tanhf(s + ck_b[wv]);
      ws[WS_QG + (i >> 4) * 1104 + 1024 + (i & 15) * 3 + wv] = 0.7f * val + 0.3f * q_ema[4096 + i * 3 + wv];
    } else if (wv == 3) {
      float val = 2.f * tanhf(s + cb_b[0]);
      ws[WS_QG + (i >> 4) * 1104 + 1072 + (i & 15)] = 0.7f * val + 0.3f * q_ema[4288 + i];
    } else if (wv == 4) {
      float val = 2.f * tanhf(s + cf_b[0]);
      ws[WS_QG + (i >> 4) * 1104 + 1088 + (i & 15)] = 0.7f * val + 0.3f * q_ema[4352 + i];
    } else {
      taup[i] = sigmoidf_(s + tau_b[0]);
    }
  }
  __syncthreads();
  if (tid < 64) {
    float t_ = taup[tid];
#pragma unroll
    for (int off = 32; off; off >>= 1) t_ += __shfl_xor(t_, off);
    if (tid == 0) ws[WS_TAU] = (t_ * (1.f / 64.f)) * 0.5f + 0.5f;
  }
}

// ================= K_B: attention scores + softmax + top-3 (one block per group) =================
__global__ __launch_bounds__(512) void kB(
    const float* __restrict__ mem_W, const float* __restrict__ temp_logit, float* __restrict__ ws) {
  __shared__ float qs[1104];
  __shared__ float part[8 * 32];
  const int tid = threadIdx.x;
  const int g = blockIdx.x;
  const int wave = tid >> 6, lane = tid & 63;
  const int dl = lane >> 3, m4 = lane & 7;
  for (int t = tid; t < 1104; t += 512) qs[t] = ws[WS_QG + g * 1104 + t];
  __syncthreads();
  const float* mwg = mem_W + (size_t)g * 1104 * 32;
  float4 a = {0.f, 0.f, 0.f, 0.f};
  for (int it = 0; it < 18; ++it) {
    int d = it * 64 + wave * 8 + dl;
    if (d < 1104) {
      float4 v4 = *(const float4*)(mwg + (size_t)d * 32 + m4 * 4);
      float qv = qs[d];
      a.x += qv * v4.x; a.y += qv * v4.y; a.z += qv * v4.z; a.w += qv * v4.w;
    }
  }
#pragma unroll
  for (int off = 8; off <= 32; off <<= 1) {
    a.x += __shfl_xor(a.x, off); a.y += __shfl_xor(a.y, off);
    a.z += __shfl_xor(a.z, off); a.w += __shfl_xor(a.w, off);
  }
  if (dl == 0) {
    float* p = part + wave * 32 + m4 * 4;
    p[0] = a.x; p[1] = a.y; p[2] = a.z; p[3] = a.w;
  }
  __syncthreads();
  if (tid < 32) {
    int m = tid;
    float att = 0.f;
#pragma unroll
    for (int w = 0; w < 8; ++w) att += part[w * 32 + m];
    float temp = 0.6f * sigmoidf_(temp_logit[g]) + 0.2f;
    att /= (temp + 1e-8f);
    float mx = att;
#pragma unroll
    for (int off = 16; off; off >>= 1) mx = fmaxf(mx, __shfl_xor(mx, off, 32));
    float e = expf(att - mx);
    float s = e;
#pragma unroll
    for (int off = 16; off; off >>= 1) s += __shfl_xor(s, off, 32);
    float p = e / s;
    for (int t = 0; t < 3; ++t) {
      float bp = p; int bm = m;
#pragma unroll
      for (int off = 16; off; off >>= 1) {
        float op = __shfl_xor(bp, off, 32);
        int om = __shfl_xor(bm, off, 32);
        if (op > bp || (op == bp && om < bm)) { bp = op; bm = om; }
      }
      if (m == 0) { ws[WS_V + g * 3 + t] = bp; ((int*)ws)[WS_IDX + g * 3 + t] = bm; }
      if (m == bm) p = -1.f;
    }
  }
}

// ================= K_D: q-final blend + beff/seff + wfrag pack (wave = one co) =================
__global__ __launch_bounds__(256) void kD(
    const float* __restrict__ mem_W, const float* __restrict__ conv_weight,
    const float* __restrict__ bias, float* __restrict__ ws) {
  __shared__ float qc1[4][64];
  __shared__ float qk1[4][4];
  const int tid = threadIdx.x;
  const int wv = tid >> 6, l = tid & 63;
  const int co = blockIdx.x * 4 + wv;
  const int g = co >> 4;
  const float tau = ws[WS_TAU];
  const float v0 = ws[WS_V + g * 3 + 0], v1 = ws[WS_V + g * 3 + 1], v2 = ws[WS_V + g * 3 + 2];
  const int x0 = ((const int*)ws)[WS_IDX + g * 3 + 0];
  const int x1 = ((const int*)ws)[WS_IDX + g * 3 + 1];
  const int x2 = ((const int*)ws)[WS_IDX + g * 3 + 2];
  const float* mwg = mem_W + (size_t)g * 1104 * 32;
  const float* qg = ws + WS_QG + g * 1104;
  {
    int d = (co & 15) * 64 + l;
    float r = v0 * mwg[(size_t)d * 32 + x0] + v1 * mwg[(size_t)d * 32 + x1] + v2 * mwg[(size_t)d * 32 + x2];
    qc1[wv][l] = 1.f + tau * qg[d] + (1.f - tau) * r;
  }
  if (l < 3) {
    int d = 1024 + (co & 15) * 3 + l;
    float r = v0 * mwg[(size_t)d * 32 + x0] + v1 * mwg[(size_t)d * 32 + x1] + v2 * mwg[(size_t)d * 32 + x2];
    qk1[wv][l] = 1.f + tau * qg[d] + (1.f - tau) * r;
  }
  if (l == 3) {
    int d = 1072 + (co & 15);
    float r = v0 * mwg[(size_t)d * 32 + x0] + v1 * mwg[(size_t)d * 32 + x1] + v2 * mwg[(size_t)d * 32 + x2];
    float qb = tau * qg[d] + (1.f - tau) * r;
    ws[WS_BEFF + co] = bias[co] * (1.f + qb);
  }
  if (l == 4) {
    int d = 1088 + (co & 15);
    float r = v0 * mwg[(size_t)d * 32 + x0] + v1 * mwg[(size_t)d * 32 + x1] + v2 * mwg[(size_t)d * 32 + x2];
    ws[WS_SEFF + co] = 1.f + tau * qg[d] + (1.f - tau) * r;
  }
  __syncthreads();
  // pack 192 wfrag entries for this co; e == kidx; ci = e&63 == l
  unsigned short* wfrag = (unsigned short*)(ws + WS_WFRAG);
  const float* cwc = conv_weight + co * 192;
#pragma unroll
  for (int kk = 0; kk < 3; ++kk) {
    int e = kk * 64 + l;
    int s = e >> 5, hi = (e >> 3) & 3, jj = e & 7;
    int f = s * 2048 + (co >> 4) * 512 + (16 * hi + (co & 15)) * 8 + jj;
    wfrag[f] = f2bf(cwc[l * 3 + kk] * qc1[wv][l] * qk1[wv][kk]);
  }
}

// ---------------- k3: conv1d as implicit GEMM via MFMA (unchanged) ----------------
__global__ __launch_bounds__(256, 3) void k3_mfma(
    const float* __restrict__ x, const unsigned short* __restrict__ wfrag,
    const float* __restrict__ beff, const float* __restrict__ seff,
    float* __restrict__ out) {
  __shared__ unsigned short xs[258 * 72];
  const int tid = threadIdx.x;
  const int w = tid >> 6, l = tid & 63;
  const int n = blockIdx.y;
  const int l0 = blockIdx.x * 256;

  bf16x8 wf[6];
#pragma unroll
  for (int s = 0; s < 6; ++s)
    wf[s] = *(const bf16x8*)(wfrag + s * 2048 + w * 512 + l * 8);

  {
    const int ci = 16 * w + (l & 15);
    const float* row = x + ((size_t)(n * 64 + ci)) * 8192 + l0;
    unsigned short* col = xs + ci;
#pragma unroll
    for (int cc = 0; cc < 16; ++cc) {
      int c = 4 * cc + (l >> 4);
      float4 v = *(const float4*)(row + 4 * c);
      col[(1 + 4 * c) * 72] = f2bf(v.x);
      col[(2 + 4 * c) * 72] = f2bf(v.y);
      col[(3 + 4 * c) * 72] = f2bf(v.z);
      col[(4 + 4 * c) * 72] = f2bf(v.w);
    }
    if (tid < 128) {
      int ci2 = tid >> 1, side = tid & 1;
      int gp = side ? (l0 + 256) : (l0 - 1);
      float v = (gp >= 0 && gp < 8192) ? x[((size_t)(n * 64 + ci2)) * 8192 + gp] : 0.f;
      xs[(side ? 257 : 0) * 72 + ci2] = f2bf(v);
    }
  }
  __syncthreads();

  f32x4 acc[16];
#pragma unroll
  for (int t = 0; t < 16; ++t) acc[t] = (f32x4){0.f, 0.f, 0.f, 0.f};

#pragma unroll
  for (int s = 0; s < 6; ++s) {
    const int kk = s >> 1;
    const int coff = (s & 1) * 32 + 8 * (l >> 4);
    const int pbase = (l & 15) + kk;
#pragma unroll
    for (int nt = 0; nt < 16; ++nt) {
      bf16x8 a = *(const bf16x8*)(xs + (nt * 16 + pbase) * 72 + coff);
      acc[nt] = __builtin_amdgcn_mfma_f32_16x16x32_bf16(a, wf[s], acc[nt], 0, 0, 0);
    }
  }

  const int co = 16 * w + (l & 15);
  const float be = beff[co], se = seff[co];
  float* orow = out + ((size_t)(n * 64 + co)) * 8192 + l0 + (l >> 4) * 4;
#pragma unroll
  for (int nt = 0; nt < 16; ++nt) {
    float4 o;
    o.x = se * (acc[nt][0] + be);
    o.y = se * (acc[nt][1] + be);
    o.z = se * (acc[nt][2] + be);
    o.w = se * (acc[nt][3] + be);
    *(float4*)(orow + nt * 16) = o;
  }
}

extern "C" void kernel_launch(void* const* d_in, const int* in_sizes, int n_in,
                              void* d_out, int out_size, void* d_ws, size_t ws_size,
                              hipStream_t stream) {
  const float* x = (const float*)d_in[0];
  const float* conv_weight = (const float*)d_in[1];
  const float* bias = (const float*)d_in[2];
  const float* grads = (const float*)d_in[3];
  const float* q_ema = (const float*)d_in[4];
  const float* ctrl_w = (const float*)d_in[5];
  const float* ctrl_b = (const float*)d_in[6];
  const float* gp_w = (const float*)d_in[7];
  const float* gp_b = (const float*)d_in[8];
  const float* gt_w = (const float*)d_in[9];
  const float* gt_b = (const float*)d_in[10];
  const float* ln_g = (const float*)d_in[11];
  const float* ln_b = (const float*)d_in[12];
  const float* ccin_w = (const float*)d_in[13];
  const float* ccin_b = (const float*)d_in[14];
  const float* ck_w = (const float*)d_in[15];
  const float* ck_b = (const float*)d_in[16];
  const float* cb_w = (const float*)d_in[17];
  const float* cb_b = (const float*)d_in[18];
  const float* cf_w = (const float*)d_in[19];
  const float* cf_b = (const float*)d_in[20];
  const float* tau_w = (const float*)d_in[21];
  const float* tau_b = (const float*)d_in[22];
  const float* mem_W = (const float*)d_in[23];
  const float* temp_logit = (const float*)d_in[24];

  float* ws = (float*)d_ws;

  hipLaunchKernelGGL(kA, dim3(1), dim3(1024), 0, stream,
                     grads, ctrl_w, ctrl_b, gp_w, gp_b, gt_w, gt_b, ln_g, ln_b,
                     ccin_w, ccin_b, ck_w, ck_b, cb_w, cb_b, cf_w, cf_b,
                     tau_w, tau_b, q_ema, ws);
  hipLaunchKernelGGL(kB, dim3(4), dim3(512), 0, stream, mem_W, temp_logit, ws);
  hipLaunchKernelGGL(kD, dim3(16), dim3(256), 0, stream, mem_W, conv_weight, bias, ws);
  hipLaunchKernelGGL(k3_mfma, dim3(32, 64), dim3(256), 0, stream,
                     x, (const unsigned short*)(ws + WS_WFRAG), ws + WS_BEFF, ws + WS_SEFF,
                     (float*)d_out);
}